// Round 1
// baseline (185.691 us; speedup 1.0000x reference)
//
#include <hip/hip_runtime.h>

// Geometry (fixed by reference)
#define NTOK 197
#define NHEADS 12
#define DIM 768
#define PP 20          // pool size
#define KK 5           // top-k
#define LL 5           // repeat per pool entry
#define STOT 397       // 197 + 200
#define BB 128

static const long long MASK_ELEMS = (long long)BB * NHEADS * NTOK * STOT; // 120129024

// ---------------- Kernel 1: inverse norms of the 40 keys at `layer` -------------
__global__ void knorm_kernel(const float* __restrict__ kc,
                             const float* __restrict__ ki,
                             const int* __restrict__ layer_p,
                             float* __restrict__ invn /*40 floats*/) {
    int layer = *layer_p;
    int kid = blockIdx.x;              // 0..39 ; 0-19 cls, 20-39 img
    const float* base = (kid < PP ? kc : ki) + (size_t)layer * PP * DIM;
    const float* kp = base + (size_t)(kid % PP) * DIM;
    int lane = threadIdx.x;            // 64 threads
    float s = 0.f;
    for (int i = lane; i < DIM; i += 64) { float v = kp[i]; s += v * v; }
    #pragma unroll
    for (int m = 1; m < 64; m <<= 1) s += __shfl_xor(s, m, 64);
    if (lane == 0) invn[kid] = 1.0f / fmaxf(sqrtf(s), 1e-12f);
}

// ---------------- Kernel 2: fused routing + mask write --------------------------
// grid: (197, 128), block: 256 threads. One block per (token t, batch b).
__global__ __launch_bounds__(256) void route_mask_kernel(
        const float* __restrict__ x,
        const float* __restrict__ kc,
        const float* __restrict__ ki,
        const int* __restrict__ layer_p,
        const float* __restrict__ invn,
        float* __restrict__ out,
        float* __restrict__ dist_ws /* [25216] */) {
    const int t = blockIdx.x;          // 0..196
    const int b = blockIdx.y;          // 0..127
    const int tok = b * NTOK + t;
    const int tid = threadIdx.x;
    const int lane = tid & 63;
    const int wv = tid >> 6;
    const int layer = *layer_p;
    const bool is_cls = (t == 0);

    const float* kb = (is_cls ? kc : ki) + (size_t)layer * PP * DIM;
    const float* invk = invn + (is_cls ? 0 : PP);
    const float* xr = x + (size_t)tok * DIM;

    // --- per-thread partial dot products (3 elements each: tid, tid+256, tid+512)
    float xv0 = xr[tid], xv1 = xr[tid + 256], xv2 = xr[tid + 512];
    float xsq = xv0 * xv0 + xv1 * xv1 + xv2 * xv2;
    float acc[PP];
    #pragma unroll
    for (int p = 0; p < PP; ++p) {
        const float* kp = kb + p * DIM;
        acc[p] = xv0 * kp[tid] + xv1 * kp[tid + 256] + xv2 * kp[tid + 512];
    }

    // --- wave butterfly reduce (all 21 values)
    #pragma unroll
    for (int m = 1; m < 64; m <<= 1) {
        xsq += __shfl_xor(xsq, m, 64);
        #pragma unroll
        for (int p = 0; p < PP; ++p) acc[p] += __shfl_xor(acc[p], m, 64);
    }

    __shared__ float red[4][PP + 1];
    __shared__ int bits_sh;
    if (lane == 0) {
        #pragma unroll
        for (int p = 0; p < PP; ++p) red[wv][p] = acc[p];
        red[wv][PP] = xsq;
    }
    __syncthreads();

    if (tid == 0) {
        float xs = red[0][PP] + red[1][PP] + red[2][PP] + red[3][PP];
        float invx = 1.0f / fmaxf(sqrtf(xs), 1e-12f);
        float sims[PP];
        #pragma unroll
        for (int p = 0; p < PP; ++p)
            sims[p] = (red[0][p] + red[1][p] + red[2][p] + red[3][p]) * invx * invk[p];
        // serial top-5; strict '>' => lowest index wins ties (lax.top_k semantics)
        int bits = 0;
        float sum5 = 0.f;
        for (int j = 0; j < KK; ++j) {
            int bi = 0; float bv = -3.0e38f;
            for (int p = 0; p < PP; ++p) {
                if (!((bits >> p) & 1) && sims[p] > bv) { bv = sims[p]; bi = p; }
            }
            bits |= (1 << bi);
            sum5 += bv;
        }
        bits_sh = bits;
        dist_ws[tok] = (float)KK - sum5;  // sum of (1 - val) over the 5 picks
    }
    __syncthreads();
    const int bits = bits_sh;

    // --- write the 397-col row for all 12 heads (identical across heads)
    const size_t hstride = (size_t)NTOK * STOT;
    const size_t rowbase = ((size_t)(b * NHEADS) * NTOK + t) * (size_t)STOT;
    for (int s = tid; s < STOT; s += 256) {
        float v;
        if (is_cls) {
            v = (s == 0) ? 1.0f
              : (s <= 100 ? (float)((bits >> ((s - 1) / 5)) & 1)
              : (s <= 200 ? 0.0f : 1.0f));
        } else {
            v = (s == 0) ? 1.0f
              : (s <= 100 ? 0.0f
              : (s <= 200 ? (float)((bits >> ((s - 101) / 5)) & 1) : 1.0f));
        }
        #pragma unroll
        for (int h = 0; h < NHEADS; ++h) {
            __builtin_nontemporal_store(v, &out[rowbase + (size_t)h * hstride + s]);
        }
    }
}

// ---------------- Kernel 3: reduce per-token dist into the output scalar --------
__global__ void reduce_dist_kernel(const float* __restrict__ dist_ws,
                                   float* __restrict__ out) {
    const int tid = threadIdx.x;   // 256 threads, single block
    float sc = 0.f, si = 0.f;
    for (int tok = tid; tok < BB * NTOK; tok += 256) {
        int q = tok / NTOK;
        int r = tok - q * NTOK;
        float v = dist_ws[tok];
        if (r == 0) sc += v; else si += v;
    }
    #pragma unroll
    for (int m = 1; m < 64; m <<= 1) {
        sc += __shfl_xor(sc, m, 64);
        si += __shfl_xor(si, m, 64);
    }
    __shared__ float lc[4], li[4];
    int lane = tid & 63, wv = tid >> 6;
    if (lane == 0) { lc[wv] = sc; li[wv] = si; }
    __syncthreads();
    if (tid == 0) {
        float c = lc[0] + lc[1] + lc[2] + lc[3];
        float i = li[0] + li[1] + li[2] + li[3];
        out[MASK_ELEMS] = c / (float)(BB * KK) + i / (float)(BB * (NTOK - 1) * KK);
    }
}

// ---------------- launcher ------------------------------------------------------
extern "C" void kernel_launch(void* const* d_in, const int* in_sizes, int n_in,
                              void* d_out, int out_size, void* d_ws, size_t ws_size,
                              hipStream_t stream) {
    const float* x  = (const float*)d_in[0];
    const float* kc = (const float*)d_in[1];
    const float* ki = (const float*)d_in[2];
    const int* layer = (const int*)d_in[3];
    float* out = (float*)d_out;

    // ws layout (floats): [0..40) invnorms, [64 .. 64+25216) per-token dist
    float* invn = (float*)d_ws;
    float* dist_ws = (float*)d_ws + 64;

    knorm_kernel<<<40, 64, 0, stream>>>(kc, ki, layer, invn);

    dim3 grid(NTOK, BB);
    route_mask_kernel<<<grid, 256, 0, stream>>>(x, kc, ki, layer, invn, out, dist_ws);

    reduce_dist_kernel<<<1, 256, 0, stream>>>(dist_ws, out);
}